// Round 1
// 258.547 us; speedup vs baseline: 1.0199x; 1.0199x over previous
//
#include <hip/hip_runtime.h>
#include <hip/hip_bf16.h>
#include <cstdint>
#include <cstddef>

// Problem constants
#define Bsz 4
#define Tsz 8192
#define Dsz 512
#define Hn 8
#define BSn 16
#define NBn 512     // T/BS blocks (attention sequence length)
#define DHn 64      // head dim
#define NQKV 1536   // 3*D
#define MROWS 32768 // B*T

// softmax scale folded with log2(e), applied to Q at gemm epilogue
#define SCL 0.06375870136f
// fixed softmax max (exp2 domain); constant offset cancels in p/sum(p)
#define ATT_M 8.0f

typedef __attribute__((ext_vector_type(8))) short short8;
typedef __attribute__((ext_vector_type(4))) float float4f;

__device__ __forceinline__ uint16_t f2b(float f) {
  union { float f; uint32_t u; } v; v.f = f;
  uint32_t u = v.u;
  return (uint16_t)((u + 0x7fffu + ((u >> 16) & 1u)) >> 16);  // RNE
}

// pack two f32 -> (bf16(b)<<16)|bf16(a), round-half-up (bias ~2^-17, negligible)
__device__ __forceinline__ uint32_t pk2(float a, float b) {
  union { float f; uint32_t u; } x, y; x.f = a; y.f = b;
  return __builtin_amdgcn_perm(y.u + 0x8000u, x.u + 0x8000u, 0x07060302u);
}

// truncating variant (softmax P only; l sums the same raw p so it stays consistent)
__device__ __forceinline__ uint32_t pk2t(float a, float b) {
  union { float f; uint32_t u; } x, y; x.f = a; y.f = b;
  return __builtin_amdgcn_perm(y.u, x.u, 0x07060302u);
}

// async 16B global -> LDS (wave-uniform LDS base + lane*16)
__device__ __forceinline__ void gl_lds16(const void* g, void* l) {
  __builtin_amdgcn_global_load_lds(
      (const __attribute__((address_space(1))) unsigned int*)g,
      (__attribute__((address_space(3))) unsigned int*)l, 16, 0, 0);
}

// ---------------- fused convert kernel (x and Wq/Wk/Wv -> bf16) ----------------
#define XBLK (MROWS * Dsz / 1024)   // 16384 blocks for x
__global__ void cvt_kernel(const float* __restrict__ x, const float* __restrict__ Wq,
                           const float* __restrict__ Wk, const float* __restrict__ Wv,
                           uint16_t* __restrict__ xb, uint16_t* __restrict__ wc) {
  int bid = blockIdx.x;
  if (bid < XBLK) {
    int i = (bid * 256 + threadIdx.x) * 4;
    float4 v = *(const float4*)(x + i);
    uint64_t o = (uint64_t)pk2(v.x, v.y) | ((uint64_t)pk2(v.z, v.w) << 32);
    *(uint64_t*)(xb + i) = o;
  } else {
    int i = ((bid - XBLK) * 256 + threadIdx.x) * 4;  // i < 1536*512
    int row = i >> 9;
    int col = i & 511;
    const float* src = (row < 512) ? Wq : ((row < 1024) ? Wk : Wv);
    float4 v = *(const float4*)(src + (size_t)(row & 511) * 512 + col);
    uint64_t o = (uint64_t)pk2(v.x, v.y) | ((uint64_t)pk2(v.z, v.w) << 32);
    *(uint64_t*)(wc + i) = o;
  }
}

// ---------------- QKV projection GEMM: 256x256, 8-phase counted-vmcnt ----------------
// Y[M=32768, N=1536] = Xb[M,512] * Wc[N,512]^T + bias.
// Grid 768 blocks (128 mt x 6 nt) of 512 threads (8 waves, 2m x 4n; wave tile 128x64).
// LDS 128KB: 2 K-tile double buffer (buf0 = even tiles, buf1 = odd), BK=64.
// K=512 -> 8 K-tiles -> 4 iterations of 8 phases (2 K-tiles each).
//
// Per-iteration schedule (iter i computes t0=2i from buf0 at ph1-4, t1=2i+1 from
// buf1 at ph5-8; quadrant order (qm,qn) = (0,0),(0,1),(1,1),(1,0) so B-fragment
// register sets b0/b1 are each loaded once from LDS and reused):
//   ph | ds_reads        | stage (2 gl_lds16)        | checkpoint
//   1  | A[qm0](8)+B0(4) | A_q1(t1)      -> buf1     |
//   2  | B1(4)           | A_q0(2i+2)    -> buf0     |
//   3  | A[qm1](8)       | B_q0(2i+2)    -> buf0     |
//   4  | -               | B_q1(2i+2)    -> buf0     | vmcnt(6)
//   5  | A[qm0](8)+B0(4) | A_q1(2i+2)    -> buf0     |
//   6  | B1(4)           | A_q0(2i+3)    -> buf1     |
//   7  | A[qm1](8)       | B_q0(2i+3)    -> buf1     |
//   8  | -               | B_q1(2i+3)    -> buf1     | vmcnt(6)
// Invariants (verified): every stage is issued >=1 barrier after the last LDS read
// of its destination region; vmcnt(6) at ph4/ph8 leaves exactly the 3 newest
// half-tiles in flight and guarantees the tile read by the following 4 phases.
// Stage halves: A_q0 = rows {0-63,128-191}, A_q1 = {64-127,192-255} (qm-phase read
// sets); B_q0 = rows {0-31,64-95,128-159,192-223}, B_q1 = +32 (qn-phase read sets).
// LDS chunk-XOR swizzle pos = c ^ (row&7), pre-swizzled on the global source
// (linear gl_lds dest, rule 21); row&7 == lrow&7 for all fragment rows.
#define BM 256
#define BN 256
#define BK 64

__global__ __launch_bounds__(512, 2) void gemm_qkv(
    const uint16_t* __restrict__ Xb, const uint16_t* __restrict__ Wc,
    const float* __restrict__ bq, const float* __restrict__ bkp,
    const float* __restrict__ bv, uint16_t* __restrict__ Qp,
    uint16_t* __restrict__ Kp, uint16_t* __restrict__ Vtmp) {
  __shared__ uint16_t As[2][BM * BK];  // 64KB
  __shared__ uint16_t Bs[2][BN * BK];  // 64KB
  const int tid = threadIdx.x;
  const int w = tid >> 6, lane = tid & 63;
  const int lrow = lane & 15, quad = lane >> 4;
  const int wm = (w >> 2) * 128, wn = (w & 3) * 64;

  // XCD swizzle: 768 = 8 XCDs x 96; each XCD owns 16 consecutive mt (6 nt each)
  int g = blockIdx.x;
  int xcd = g & 7, ii = g >> 3;        // ii in [0,96)
  int mt = xcd * 16 + ii / 6;
  int nt = ii - (ii / 6) * 6;
  const int m0 = mt * BM;
  const int n0 = nt * BN;

  // staging precompute: per-thread source row/chunk (swizzled k offset)
  const int r6 = tid >> 3;                          // 0..63 row-in-pass
  const int kc = ((tid & 7) ^ (r6 & 7)) * 8;        // swizzled k-chunk (elems)
  const uint16_t* gA = Xb + (size_t)(m0 + r6) * 512 + kc;
  const int rbB = ((r6 >> 5) * 64) + (r6 & 31);
  const uint16_t* gB = Wc + (size_t)(n0 + rbB) * 512 + kc;
  const int lbA = (w * 8) * 64;                         // wave-uniform LDS row base
  const int lbB = ((w >> 2) * 64 + (w & 3) * 8) * 64;

#define STAGE_A(buf, tile, half) do {                                         \
    const int k0_ = (tile) * 64;                                              \
    gl_lds16(gA + (size_t)((half) * 64) * 512 + k0_,                          \
             &As[buf][((half) * 64) * 64 + lbA]);                             \
    gl_lds16(gA + (size_t)((half) * 64 + 128) * 512 + k0_,                    \
             &As[buf][((half) * 64 + 128) * 64 + lbA]);                       \
  } while (0)

#define STAGE_B(buf, tile, half) do {                                         \
    const int k0_ = (tile) * 64;                                              \
    gl_lds16(gB + (size_t)((half) * 32) * 512 + k0_,                          \
             &Bs[buf][((half) * 32) * 64 + lbB]);                             \
    gl_lds16(gB + (size_t)((half) * 32 + 128) * 512 + k0_,                    \
             &Bs[buf][((half) * 32 + 128) * 64 + lbB]);                       \
  } while (0)

  short8 a[4][2], b0[2][2], b1[2][2];
  float4f acc[2][2][4][2] = {};  // [qm][qn][i m-sub][j n-sub]

#define LOAD_A(buf, qm) do {                                                  \
    _Pragma("unroll") for (int i_ = 0; i_ < 4; ++i_) {                        \
      const uint16_t* p_ = &As[buf][(wm + (qm) * 64 + i_ * 16 + lrow) * 64];  \
      a[i_][0] = *(const short8*)(p_ + ((quad ^ (lrow & 7)) * 8));            \
      a[i_][1] = *(const short8*)(p_ + (((4 + quad) ^ (lrow & 7)) * 8));      \
    } } while (0)

#define LOAD_B(buf, qn, bb_) do {                                             \
    _Pragma("unroll") for (int j_ = 0; j_ < 2; ++j_) {                        \
      const uint16_t* p_ = &Bs[buf][(wn + (qn) * 32 + j_ * 16 + lrow) * 64];  \
      bb_[j_][0] = *(const short8*)(p_ + ((quad ^ (lrow & 7)) * 8));          \
      bb_[j_][1] = *(const short8*)(p_ + (((4 + quad) ^ (lrow & 7)) * 8));    \
    } } while (0)

#define MFMA16(QM, QN, BB) do {                                               \
    _Pragma("unroll") for (int h_ = 0; h_ < 2; ++h_)                          \
    _Pragma("unroll") for (int i_ = 0; i_ < 4; ++i_)                          \
    _Pragma("unroll") for (int j_ = 0; j_ < 2; ++j_)                          \
      acc[QM][QN][i_][j_] = __builtin_amdgcn_mfma_f32_16x16x32_bf16(          \
          a[i_][h_], BB[j_][h_], acc[QM][QN][i_][j_], 0, 0, 0);               \
  } while (0)

#define PH_MID() do { __builtin_amdgcn_sched_barrier(0);                      \
    __builtin_amdgcn_s_barrier(); __builtin_amdgcn_s_setprio(1); } while (0)
#define PH_END() do { __builtin_amdgcn_s_setprio(0);                          \
    __builtin_amdgcn_sched_barrier(0); __builtin_amdgcn_s_barrier();          \
    __builtin_amdgcn_sched_barrier(0); } while (0)
#define PH_END_VMC(N) do { __builtin_amdgcn_s_setprio(0);                     \
    __builtin_amdgcn_sched_barrier(0);                                        \
    asm volatile("s_waitcnt vmcnt(" #N ")" ::: "memory");                     \
    __builtin_amdgcn_s_barrier();                                             \
    __builtin_amdgcn_sched_barrier(0); } while (0)

  // prologue: tile0 full (8 loads) + tile1 {A_q0,B_q0,B_q1} (6 loads)
  STAGE_A(0, 0, 0); STAGE_A(0, 0, 1); STAGE_B(0, 0, 0); STAGE_B(0, 0, 1);
  STAGE_A(1, 1, 0); STAGE_B(1, 1, 0); STAGE_B(1, 1, 1);
  asm volatile("s_waitcnt vmcnt(6)" ::: "memory");  // tile0 landed
  __builtin_amdgcn_s_barrier();
  __builtin_amdgcn_sched_barrier(0);

#pragma unroll 1
  for (int it = 0; it < 4; ++it) {
    const int t1 = 2 * it + 1;
    const bool more = (it < 3);
    // ---- phase 1: (0,0) buf0 ----
    LOAD_A(0, 0); LOAD_B(0, 0, b0);
    STAGE_A(1, t1, 1);                 // completes tile t1
    PH_MID(); MFMA16(0, 0, b0); PH_END();
    // ---- phase 2: (0,1) buf0 ----
    LOAD_B(0, 1, b1);
    if (more) STAGE_A(0, t1 + 1, 0);
    PH_MID(); MFMA16(0, 1, b1); PH_END();
    // ---- phase 3: (1,1) buf0 ----
    LOAD_A(0, 1);
    if (more) STAGE_B(0, t1 + 1, 0);
    PH_MID(); MFMA16(1, 1, b1); PH_END();
    // ---- phase 4: (1,0) buf0, checkpoint: tile t1 fully landed ----
    if (more) STAGE_B(0, t1 + 1, 1);
    PH_MID(); MFMA16(1, 0, b0);
    if (more) PH_END_VMC(6); else PH_END_VMC(0);
    // ---- phase 5: (0,0) buf1 ----
    LOAD_A(1, 0); LOAD_B(1, 0, b0);
    if (more) STAGE_A(0, t1 + 1, 1);   // completes tile 2i+2
    PH_MID(); MFMA16(0, 0, b0); PH_END();
    // ---- phase 6: (0,1) buf1 ----
    LOAD_B(1, 1, b1);
    if (more) STAGE_A(1, t1 + 2, 0);
    PH_MID(); MFMA16(0, 1, b1); PH_END();
    // ---- phase 7: (1,1) buf1 ----
    LOAD_A(1, 1);
    if (more) STAGE_B(1, t1 + 2, 0);
    PH_MID(); MFMA16(1, 1, b1); PH_END();
    // ---- phase 8: (1,0) buf1, checkpoint: tile 2i+2 fully landed ----
    if (more) STAGE_B(1, t1 + 2, 1);
    PH_MID(); MFMA16(1, 0, b0);
    if (more) PH_END_VMC(6); else PH_END();
  }

  // ---------------- epilogue (round-3 store pattern, extended to 2x2 quadrants)
  const int region = n0 >> 9;  // 0=Q, 1=K, 2=V (256 | 512, no tile crosses)
  const float* bias = (region == 0) ? bq : ((region == 1) ? bkp : bv);

  if (region < 2) {
    uint16_t* dst = (region == 0) ? Qp : Kp;
    const float mult = (region == 0) ? SCL : 1.0f;
#pragma unroll
    for (int qm = 0; qm < 2; ++qm) {
      const int tokb = m0 + wm + qm * 64;
      const int bb = tokb >> 13;
      const int nbb = (tokb >> 4) & 511;
      const size_t base0 = (size_t)bb * 4194304 + (size_t)nbb * 64 +
                           (size_t)(quad * 4) * 262144;
#pragma unroll
      for (int qn = 0; qn < 2; ++qn)
#pragma unroll
        for (int j = 0; j < 2; ++j) {
          const int nl = (n0 & 511) + wn + qn * 32 + j * 16 + lrow;
          const int hh = nl >> 6, dh = nl & 63;
          const float bval = bias[nl];
          const size_t base = base0 + (size_t)hh * 32768 + dh;
#pragma unroll
          for (int i2 = 0; i2 < 4; ++i2)
#pragma unroll
            for (int r = 0; r < 4; ++r)
              dst[base + (size_t)r * 262144 + (size_t)i2 * 64] =
                  f2b((acc[qm][qn][i2][j][r] + bval) * mult);
        }
    }
  } else {
#pragma unroll
    for (int qm = 0; qm < 2; ++qm) {
      const int tokb = m0 + wm + qm * 64 + quad * 4;
#pragma unroll
      for (int qn = 0; qn < 2; ++qn)
#pragma unroll
        for (int j = 0; j < 2; ++j) {
          const int nl = (n0 & 511) + wn + qn * 32 + j * 16 + lrow;
          const float bval = bias[nl];
#pragma unroll
          for (int i2 = 0; i2 < 4; ++i2) {
            const int tok = tokb + i2 * 16;
#pragma unroll
            for (int r = 0; r < 4; ++r)
              Vtmp[(size_t)(tok + r) * 512 + nl] = f2b(acc[qm][qn][i2][j][r] + bval);
          }
        }
    }
  }
#undef STAGE_A
#undef STAGE_B
#undef LOAD_A
#undef LOAD_B
#undef MFMA16
#undef PH_MID
#undef PH_END
#undef PH_END_VMC
}

// ---------------- V transpose: Vtmp[32768][512] -> Vt[(b,s,h)][dh=64][nb=512] ----------------
__global__ __launch_bounds__(256) void vtrans(const uint16_t* __restrict__ Vtmp,
                                              uint16_t* __restrict__ Vt) {
  __shared__ uint16_t tile[64 * 64];  // [nb_local][dh], 16B chunks XOR-swizzled by row
  int bx = blockIdx.x;
  const int nt = bx & 7; bx >>= 3;
  const int h = bx & 7; bx >>= 3;
  const int s = bx & 15;
  const int b = bx >> 4;
  const int tid = threadIdx.x;

  {  // read 64 tokens x 64 dh; thread: row i, two 16B chunks
    int i = tid >> 2;
    int token = b * Tsz + (nt * 64 + i) * BSn + s;
    const uint16_t* src = Vtmp + (size_t)token * 512 + h * 64;
#pragma unroll
    for (int hh = 0; hh < 2; ++hh) {
      int ch = (tid & 3) * 2 + hh;
      short8 v = *(const short8*)(src + ch * 8);
      int pc = ch ^ (i & 7);
      *(short8*)(tile + i * 64 + pc * 8) = v;
    }
  }
  __syncthreads();
  {  // write: wave-major dh for conflict-free column gather
    int dh = tid & 63, seg = tid >> 6;
    short8 v1, v2;
#pragma unroll
    for (int k = 0; k < 8; ++k) {
      int nb_l = seg * 16 + k;
      v1[k] = (short)tile[nb_l * 64 + (((dh >> 3) ^ (nb_l & 7)) * 8) + (dh & 7)];
    }
#pragma unroll
    for (int k = 0; k < 8; ++k) {
      int nb_l = seg * 16 + 8 + k;
      v2[k] = (short)tile[nb_l * 64 + (((dh >> 3) ^ (nb_l & 7)) * 8) + (dh & 7)];
    }
    size_t obase = ((((size_t)b * 16 + s) * 8 + h) * 64 + dh) * 512 + nt * 64 + seg * 16;
    *(short8*)(Vt + obase) = v1;
    *(short8*)(Vt + obase + 8) = v2;
  }
}

// ---------------- fused block attention, S^T orientation, fixed-max softmax ----------------
__global__ __launch_bounds__(256, 3) void attn_kernel(
    const uint16_t* __restrict__ Qp, const uint16_t* __restrict__ Kp,
    const uint16_t* __restrict__ Vt, float* __restrict__ out) {
  __shared__ uint16_t Ks[32 * 64];        // K tile, rows 128B, chunk pos = c ^ (r&7)
  __shared__ uint16_t Vs[64 * 32];        // V^T tile, rows 64B, pos = c ^ ((r>>1)&3)
  __shared__ uint16_t Ps[4][4][16 * 32];  // [wave][qs] P [q][kv], pos = c ^ ((q>>1)&3)

  int bx = blockIdx.x;
  const int qh = bx & 1; bx >>= 1;
  const int h = bx & 7; bx >>= 3;
  const int s = bx & 15;
  const int b = bx >> 4;

  const int tid = threadIdx.x;
  const int w = tid >> 6, lane = tid & 63;
  const int lrow = lane & 15, quad = lane >> 4;

  const size_t sh = (((size_t)b * 16 + s) * 8 + h);
  const uint16_t* Qb = Qp + (sh << 15);   // [512 nb][64 dh]
  const uint16_t* Kb = Kp + (sh << 15);   // [512 nb][64 dh]
  const uint16_t* Vb = Vt + (sh << 15);   // [64 dh][512 nb]

  // Q B-fragments (persistent): 4 q-subtiles x 2 dh-chunks
  short8 qB[4][2];
  const int q0 = qh * 256 + w * 64;
#pragma unroll
  for (int qs = 0; qs < 4; ++qs) {
    const uint16_t* qp = Qb + (size_t)(q0 + qs * 16 + lrow) * 64;
    qB[qs][0] = *(const short8*)(qp + quad * 8);
    qB[qs][1] = *(const short8*)(qp + 32 + quad * 8);
  }

  float4f O[4][4] = {};                 // [dh tile][q subtile], C-layout (col=q)
  float l_acc[4] = {0.f, 0.f, 0.f, 0.f};

  const int kr = w * 8 + (lane >> 3);
  const int kcs = (lane & 7) ^ (kr & 7);
  const int vr = w * 16 + (lane >> 2);
  const int vcs = (lane & 3) ^ ((vr >> 1) & 3);

  const int sw = (lrow >> 1) & 3;
  const float4f negm = {-ATT_M, -ATT_M, -ATT_M, -ATT_M};

  for (int kv0 = 0; kv0 < NBn; kv0 += 32) {
    __syncthreads();
    gl_lds16(Kb + (size_t)(kv0 + kr) * 64 + kcs * 8, Ks + w * 512);
    gl_lds16(Vb + (size_t)vr * 512 + kv0 + vcs * 8, Vs + w * 512);
    __syncthreads();

    // ---- S-phase: K A-fragments, scores, exp2, pack into Ps ----
    {
      short8 kA[2][2];
#pragma unroll
      for (int kt = 0; kt < 2; ++kt) {
        int row = kt * 16 + lrow;
#pragma unroll
        for (int kc = 0; kc < 2; ++kc) {
          int cc = (kc * 4 + quad) ^ (row & 7);
          kA[kt][kc] = *(const short8*)(Ks + row * 64 + cc * 8);
        }
      }
#pragma unroll
      for (int qs = 0; qs < 4; ++qs) {
        // C pre-loaded with -M: exp2 args come out of MFMA directly
        float4f c0 = negm, c1 = negm;
        c0 = __builtin_amdgcn_mfma_f32_16x16x32_bf16(kA[0][0], qB[qs][0], c0, 0, 0, 0);
        c0 = __builtin_amdgcn_mfma_f32_16x16x32_bf16(kA[0][1], qB[qs][1], c0, 0, 0, 0);
        c1 = __builtin_amdgcn_mfma_f32_16x16x32_bf16(kA[1][0], qB[qs][0], c1, 0, 0, 0);
        c1 = __builtin_amdgcn_mfma_f32_16x16x32_bf16(kA[1][1], qB[qs][1], c1, 0, 0, 0);

        float p00 = __builtin_amdgcn_exp2f(c0[0]);
        float p01 = __builtin_amdgcn_exp2f(c0[1]);
        float p02 = __builtin_amdgcn_exp2f(c0[2]);
        float p03 = __builtin_amdgcn_exp2f(c0[3]);
        float p10 = __builtin_amdgcn_exp2f(c1[0]);
        float p11 = __builtin_amdgcn_exp2f(c1[1]);
        float p12 = __builtin_amdgcn_exp2f(c1[2]);
        float p13 = __builtin_amdgcn_exp2f(c1[3]);
        l_acc[qs] += ((p00 + p01) + (p02 + p03)) + ((p10 + p11) + (p12 + p13));

        uint32_t d0 = pk2t(p00, p01), d1 = pk2t(p02, p03);
        uint32_t d2 = pk2t(p10, p11), d3 = pk2t(p12, p13);
        uint16_t* Psq = Ps[w][qs];
        int half = (quad & 1) * 4;
        *(uint2*)(Psq + lrow * 32 + (((quad >> 1)) ^ sw) * 8 + half) = make_uint2(d0, d1);
        *(uint2*)(Psq + lrow * 32 + ((2 + (quad >> 1)) ^ sw) * 8 + half) = make_uint2(d2, d3);
      }
    }

    // ---- PV-phase: V^T A-fragments, P B-fragments, accumulate O ----
    {
      short8 vA[4];
#pragma unroll
      for (int dt = 0; dt < 4; ++dt) {
        int row = dt * 16 + lrow;
        vA[dt] = *(const short8*)(Vs + row * 32 + (quad ^ ((row >> 1) & 3)) * 8);
      }
#pragma unroll
      for (int qs = 0; qs < 4; ++qs) {
        short8 pB = *(const short8*)(Ps[w][qs] + lrow * 32 + (quad ^ sw) * 8);
#pragma unroll
        for (int dt = 0; dt < 4; ++dt)
          O[dt][qs] = __builtin_amdgcn_mfma_f32_16x16x32_bf16(vA[dt], pB, O[dt][qs], 0, 0, 0);
      }
    }
  }

  // epilogue: reduce l across quads (kv partials), normalize, write fp32
#pragma unroll
  for (int qs = 0; qs < 4; ++qs) {
    float l = l_acc[qs];
    l += __shfl_xor(l, 16);
    l += __shfl_xor(l, 32);
    float inv = 1.0f / l;
    int qg = q0 + qs * 16 + lrow;   // nb index of this lane's q column
    float* op = out + ((size_t)b * Tsz + (size_t)qg * 16 + s) * Dsz + h * 64;
#pragma unroll
    for (int dt = 0; dt < 4; ++dt) {
      float4 vv;
      vv.x = O[dt][qs][0] * inv; vv.y = O[dt][qs][1] * inv;
      vv.z = O[dt][qs][2] * inv; vv.w = O[dt][qs][3] * inv;
      *(float4*)(op + dt * 16 + quad * 4) = vv;
    }
  }
}

// ---------------- launch ----------------
extern "C" void kernel_launch(void* const* d_in, const int* in_sizes, int n_in,
                              void* d_out, int out_size, void* d_ws, size_t ws_size,
                              hipStream_t stream) {
  const float* x  = (const float*)d_in[0];
  const float* Wq = (const float*)d_in[1];
  const float* bq = (const float*)d_in[2];
  const float* Wk = (const float*)d_in[3];
  const float* bk = (const float*)d_in[4];
  const float* Wv = (const float*)d_in[5];
  const float* bv = (const float*)d_in[6];
  float* out = (float*)d_out;

  // workspace: Qp | Kp | Vtmp | xb | wc ; Vt aliases xb (gemm done with xb first)
  uint16_t* Qp   = (uint16_t*)d_ws;
  uint16_t* Kp   = Qp + (size_t)16777216;
  uint16_t* Vtmp = Kp + (size_t)16777216;
  uint16_t* xb   = Vtmp + (size_t)16777216;
  uint16_t* wc   = xb + (size_t)16777216;
  uint16_t* Vt   = xb;  // alias

  hipLaunchKernelGGL(cvt_kernel, dim3(XBLK + NQKV * Dsz / 1024), dim3(256), 0, stream,
                     x, Wq, Wk, Wv, xb, wc);
  hipLaunchKernelGGL(gemm_qkv, dim3((MROWS / BM) * (NQKV / BN)), dim3(512), 0, stream,
                     xb, wc, bq, bk, bv, Qp, Kp, Vtmp);
  hipLaunchKernelGGL(vtrans, dim3(Bsz * BSn * Hn * 8), dim3(256), 0, stream, Vtmp, Vt);
  hipLaunchKernelGGL(attn_kernel, dim3(Bsz * BSn * Hn * 2), dim3(256), 0, stream,
                     Qp, Kp, Vt, out);
}

// Round 2
// 257.876 us; speedup vs baseline: 1.0225x; 1.0026x over previous
//
#include <hip/hip_runtime.h>
#include <hip/hip_bf16.h>
#include <cstdint>
#include <cstddef>

// Problem constants
#define Bsz 4
#define Tsz 8192
#define Dsz 512
#define Hn 8
#define BSn 16
#define NBn 512     // T/BS blocks (attention sequence length)
#define DHn 64      // head dim
#define NQKV 1536   // 3*D
#define MROWS 32768 // B*T

// softmax scale folded with log2(e), applied to Q at gemm epilogue
#define SCL 0.06375870136f
// fixed softmax max (exp2 domain); constant offset cancels in p/sum(p)
#define ATT_M 8.0f

typedef __attribute__((ext_vector_type(8))) short short8;
typedef __attribute__((ext_vector_type(4))) float float4f;

__device__ __forceinline__ uint16_t f2b(float f) {
  union { float f; uint32_t u; } v; v.f = f;
  uint32_t u = v.u;
  return (uint16_t)((u + 0x7fffu + ((u >> 16) & 1u)) >> 16);  // RNE
}

// pack two f32 -> (bf16(b)<<16)|bf16(a), round-half-up (bias ~2^-17, negligible)
__device__ __forceinline__ uint32_t pk2(float a, float b) {
  union { float f; uint32_t u; } x, y; x.f = a; y.f = b;
  return __builtin_amdgcn_perm(y.u + 0x8000u, x.u + 0x8000u, 0x07060302u);
}

// truncating variant (softmax P only; l sums the same raw p so it stays consistent)
__device__ __forceinline__ uint32_t pk2t(float a, float b) {
  union { float f; uint32_t u; } x, y; x.f = a; y.f = b;
  return __builtin_amdgcn_perm(y.u, x.u, 0x07060302u);
}

// async 16B global -> LDS (wave-uniform LDS base + lane*16)
__device__ __forceinline__ void gl_lds16(const void* g, void* l) {
  __builtin_amdgcn_global_load_lds(
      (const __attribute__((address_space(1))) unsigned int*)g,
      (__attribute__((address_space(3))) unsigned int*)l, 16, 0, 0);
}

// ---------------- fused convert kernel (x and Wq/Wk/Wv -> bf16) ----------------
#define XBLK (MROWS * Dsz / 1024)   // 16384 blocks for x
__global__ void cvt_kernel(const float* __restrict__ x, const float* __restrict__ Wq,
                           const float* __restrict__ Wk, const float* __restrict__ Wv,
                           uint16_t* __restrict__ xb, uint16_t* __restrict__ wc) {
  int bid = blockIdx.x;
  if (bid < XBLK) {
    int i = (bid * 256 + threadIdx.x) * 4;
    float4 v = *(const float4*)(x + i);
    uint64_t o = (uint64_t)pk2(v.x, v.y) | ((uint64_t)pk2(v.z, v.w) << 32);
    *(uint64_t*)(xb + i) = o;
  } else {
    int i = ((bid - XBLK) * 256 + threadIdx.x) * 4;  // i < 1536*512
    int row = i >> 9;
    int col = i & 511;
    const float* src = (row < 512) ? Wq : ((row < 1024) ? Wk : Wv);
    float4 v = *(const float4*)(src + (size_t)(row & 511) * 512 + col);
    uint64_t o = (uint64_t)pk2(v.x, v.y) | ((uint64_t)pk2(v.z, v.w) << 32);
    *(uint64_t*)(wc + i) = o;
  }
}

// ---------------- QKV projection GEMM ----------------
// Y[M=32768, N=1536] = Xb[M,512] * Wc[N,512]^T + bias.
// Round-3 2-phase structure (proven: inter-block TLP hides barrier drains at
// K=512; the 8-phase 256^2 port regressed -- 1 block/CU, fill/drain exposed).
// Tile upgraded 128x64 -> 128x128: per K-step per wave 32 MFMAs (was 16) vs
// 16 ds_reads (was 12) and the same 2 barriers; B staging per block halves.
// LDS 32KB -> 4-5 blocks/CU resident (launch_bounds(256,4); acc = 64 AGPRs).
#define BM 128
#define BN 128
#define BK 64

__global__ __launch_bounds__(256, 4) void gemm_qkv(
    const uint16_t* __restrict__ Xb, const uint16_t* __restrict__ Wc,
    const float* __restrict__ bq, const float* __restrict__ bkp,
    const float* __restrict__ bv, uint16_t* __restrict__ Qp,
    uint16_t* __restrict__ Kp, uint16_t* __restrict__ Vtmp) {
  __shared__ uint16_t As[BM * BK];  // 16KB, row=64 elems=8 chunks, pos = c ^ (row&7)
  __shared__ uint16_t Bs[BN * BK];  // 16KB
  const int tid = threadIdx.x;
  const int wave = tid >> 6, lane = tid & 63;
  const int lrow = lane & 15, quad = lane >> 4;

  // XCD swizzle: 12 n-blocks of one m-slice stay consecutive on one XCD.
  int g = blockIdx.x;
  int xcd = g & 7, ii = g >> 3;        // ii in [0,384)
  int mt = xcd * 32 + ii / 12;
  int nt = ii - (ii / 12) * 12;
  const int m0 = mt * BM;
  const int n0 = nt * BN;
  const int wm = (wave >> 1) * 64, wn = (wave & 1) * 64;  // wave tile 64m x 64n

  float4f acc[4][4] = {};   // [i: m-subtile][j: n-subtile]

  for (int k0 = 0; k0 < Dsz; k0 += BK) {
    __syncthreads();
#pragma unroll
    for (int p = 0; p < 4; ++p) {       // As: 1024 chunks
      int cbase = p * 256 + wave * 64;
      int c = cbase + lane;
      int row = c >> 3, pos = c & 7;
      int kc = (pos ^ (row & 7)) * 8;   // swizzle on the GLOBAL side (free)
      gl_lds16(Xb + (size_t)(m0 + row) * Dsz + k0 + kc, As + cbase * 8);
    }
#pragma unroll
    for (int p = 0; p < 4; ++p) {       // Bs: 1024 chunks
      int cbase = p * 256 + wave * 64;
      int c = cbase + lane;
      int row = c >> 3, pos = c & 7;
      int kc = (pos ^ (row & 7)) * 8;
      gl_lds16(Wc + (size_t)(n0 + row) * Dsz + k0 + kc, Bs + cbase * 8);
    }
    __syncthreads();

#pragma unroll
    for (int h = 0; h < 2; ++h) {
      short8 af[4], bf[4];
#pragma unroll
      for (int i = 0; i < 4; ++i) {
        int rowA = wm + i * 16 + lrow;
        af[i] = *(const short8*)(As + rowA * BK + (((h * 4 + quad) ^ (rowA & 7)) * 8));
      }
#pragma unroll
      for (int j = 0; j < 4; ++j) {
        int rowB = wn + j * 16 + lrow;
        bf[j] = *(const short8*)(Bs + rowB * BK + (((h * 4 + quad) ^ (rowB & 7)) * 8));
      }
#pragma unroll
      for (int i = 0; i < 4; ++i)
#pragma unroll
        for (int j = 0; j < 4; ++j)
          acc[i][j] = __builtin_amdgcn_mfma_f32_16x16x32_bf16(af[i], bf[j], acc[i][j], 0, 0, 0);
    }
  }

  // epilogue (round-3 pattern): token s = quad*4+r, dh consecutive over lrow
  const int region = n0 >> 9;  // 0=Q, 1=K, 2=V (128 | 512 so no tile crosses)
  const float* bias = (region == 0) ? bq : ((region == 1) ? bkp : bv);
  const float mult = (region == 0) ? SCL : 1.0f;
  const int bb = m0 >> 13;
  const int nbbase = ((m0 & 8191) >> 4) + (wm >> 4);    // nb = nbbase + i
  const int nv0 = (n0 & 511) + wn;

  if (region < 2) {
    uint16_t* dst = (region == 0) ? Qp : Kp;
#pragma unroll
    for (int j = 0; j < 4; ++j) {
      int nl = nv0 + j * 16 + lrow;
      int hh = nl >> 6, dh = nl & 63;
      float bval = bias[nl];
      // addr = ((b*16+s)*8+h)*32768 + nb*64 + dh  (s = quad*4+r)
      size_t base = (size_t)bb * 4194304 + (size_t)hh * 32768 +
                    (size_t)nbbase * 64 + dh + (size_t)(quad * 4) * 262144;
#pragma unroll
      for (int i = 0; i < 4; ++i)
#pragma unroll
        for (int r = 0; r < 4; ++r)
          dst[base + (size_t)r * 262144 + (size_t)i * 64] =
              f2b((acc[i][j][r] + bval) * mult);
    }
  } else {
#pragma unroll
    for (int j = 0; j < 4; ++j) {
      int nl = nv0 + j * 16 + lrow;
      float bval = bias[nl];
#pragma unroll
      for (int i = 0; i < 4; ++i) {
        int tok = m0 + wm + i * 16 + quad * 4;
#pragma unroll
        for (int r = 0; r < 4; ++r)
          Vtmp[(size_t)(tok + r) * 512 + nl] = f2b(acc[i][j][r] + bval);
      }
    }
  }
}

// ---------------- V transpose: Vtmp[32768][512] -> Vt[(b,s,h)][dh=64][nb=512] ----------------
__global__ __launch_bounds__(256) void vtrans(const uint16_t* __restrict__ Vtmp,
                                              uint16_t* __restrict__ Vt) {
  __shared__ uint16_t tile[64 * 64];  // [nb_local][dh], 16B chunks XOR-swizzled by row
  int bx = blockIdx.x;
  const int nt = bx & 7; bx >>= 3;
  const int h = bx & 7; bx >>= 3;
  const int s = bx & 15;
  const int b = bx >> 4;
  const int tid = threadIdx.x;

  {  // read 64 tokens x 64 dh; thread: row i, two 16B chunks
    int i = tid >> 2;
    int token = b * Tsz + (nt * 64 + i) * BSn + s;
    const uint16_t* src = Vtmp + (size_t)token * 512 + h * 64;
#pragma unroll
    for (int hh = 0; hh < 2; ++hh) {
      int ch = (tid & 3) * 2 + hh;
      short8 v = *(const short8*)(src + ch * 8);
      int pc = ch ^ (i & 7);
      *(short8*)(tile + i * 64 + pc * 8) = v;
    }
  }
  __syncthreads();
  {  // write: wave-major dh for conflict-free column gather
    int dh = tid & 63, seg = tid >> 6;
    short8 v1, v2;
#pragma unroll
    for (int k = 0; k < 8; ++k) {
      int nb_l = seg * 16 + k;
      v1[k] = (short)tile[nb_l * 64 + (((dh >> 3) ^ (nb_l & 7)) * 8) + (dh & 7)];
    }
#pragma unroll
    for (int k = 0; k < 8; ++k) {
      int nb_l = seg * 16 + 8 + k;
      v2[k] = (short)tile[nb_l * 64 + (((dh >> 3) ^ (nb_l & 7)) * 8) + (dh & 7)];
    }
    size_t obase = ((((size_t)b * 16 + s) * 8 + h) * 64 + dh) * 512 + nt * 64 + seg * 16;
    *(short8*)(Vt + obase) = v1;
    *(short8*)(Vt + obase + 8) = v2;
  }
}

// ---------------- fused block attention, S^T orientation, fixed-max softmax ----------------
__global__ __launch_bounds__(256, 3) void attn_kernel(
    const uint16_t* __restrict__ Qp, const uint16_t* __restrict__ Kp,
    const uint16_t* __restrict__ Vt, float* __restrict__ out) {
  __shared__ uint16_t Ks[32 * 64];        // K tile, rows 128B, chunk pos = c ^ (r&7)
  __shared__ uint16_t Vs[64 * 32];        // V^T tile, rows 64B, pos = c ^ ((r>>1)&3)
  __shared__ uint16_t Ps[4][4][16 * 32];  // [wave][qs] P [q][kv], pos = c ^ ((q>>1)&3)

  int bx = blockIdx.x;
  const int qh = bx & 1; bx >>= 1;
  const int h = bx & 7; bx >>= 3;
  const int s = bx & 15;
  const int b = bx >> 4;

  const int tid = threadIdx.x;
  const int w = tid >> 6, lane = tid & 63;
  const int lrow = lane & 15, quad = lane >> 4;

  const size_t sh = (((size_t)b * 16 + s) * 8 + h);
  const uint16_t* Qb = Qp + (sh << 15);   // [512 nb][64 dh]
  const uint16_t* Kb = Kp + (sh << 15);   // [512 nb][64 dh]
  const uint16_t* Vb = Vt + (sh << 15);   // [64 dh][512 nb]

  // Q B-fragments (persistent): 4 q-subtiles x 2 dh-chunks
  short8 qB[4][2];
  const int q0 = qh * 256 + w * 64;
#pragma unroll
  for (int qs = 0; qs < 4; ++qs) {
    const uint16_t* qp = Qb + (size_t)(q0 + qs * 16 + lrow) * 64;
    qB[qs][0] = *(const short8*)(qp + quad * 8);
    qB[qs][1] = *(const short8*)(qp + 32 + quad * 8);
  }

  float4f O[4][4] = {};                 // [dh tile][q subtile], C-layout (col=q)
  float l_acc[4] = {0.f, 0.f, 0.f, 0.f};

  const int kr = w * 8 + (lane >> 3);
  const int kcs = (lane & 7) ^ (kr & 7);
  const int vr = w * 16 + (lane >> 2);
  const int vcs = (lane & 3) ^ ((vr >> 1) & 3);

  const int sw = (lrow >> 1) & 3;
  const float4f negm = {-ATT_M, -ATT_M, -ATT_M, -ATT_M};

  for (int kv0 = 0; kv0 < NBn; kv0 += 32) {
    __syncthreads();
    gl_lds16(Kb + (size_t)(kv0 + kr) * 64 + kcs * 8, Ks + w * 512);
    gl_lds16(Vb + (size_t)vr * 512 + kv0 + vcs * 8, Vs + w * 512);
    __syncthreads();

    // ---- S-phase: K A-fragments, scores, exp2, pack into Ps ----
    {
      short8 kA[2][2];
#pragma unroll
      for (int kt = 0; kt < 2; ++kt) {
        int row = kt * 16 + lrow;
#pragma unroll
        for (int kc = 0; kc < 2; ++kc) {
          int cc = (kc * 4 + quad) ^ (row & 7);
          kA[kt][kc] = *(const short8*)(Ks + row * 64 + cc * 8);
        }
      }
#pragma unroll
      for (int qs = 0; qs < 4; ++qs) {
        // C pre-loaded with -M: exp2 args come out of MFMA directly
        float4f c0 = negm, c1 = negm;
        c0 = __builtin_amdgcn_mfma_f32_16x16x32_bf16(kA[0][0], qB[qs][0], c0, 0, 0, 0);
        c0 = __builtin_amdgcn_mfma_f32_16x16x32_bf16(kA[0][1], qB[qs][1], c0, 0, 0, 0);
        c1 = __builtin_amdgcn_mfma_f32_16x16x32_bf16(kA[1][0], qB[qs][0], c1, 0, 0, 0);
        c1 = __builtin_amdgcn_mfma_f32_16x16x32_bf16(kA[1][1], qB[qs][1], c1, 0, 0, 0);

        float p00 = __builtin_amdgcn_exp2f(c0[0]);
        float p01 = __builtin_amdgcn_exp2f(c0[1]);
        float p02 = __builtin_amdgcn_exp2f(c0[2]);
        float p03 = __builtin_amdgcn_exp2f(c0[3]);
        float p10 = __builtin_amdgcn_exp2f(c1[0]);
        float p11 = __builtin_amdgcn_exp2f(c1[1]);
        float p12 = __builtin_amdgcn_exp2f(c1[2]);
        float p13 = __builtin_amdgcn_exp2f(c1[3]);
        l_acc[qs] += ((p00 + p01) + (p02 + p03)) + ((p10 + p11) + (p12 + p13));

        uint32_t d0 = pk2t(p00, p01), d1 = pk2t(p02, p03);
        uint32_t d2 = pk2t(p10, p11), d3 = pk2t(p12, p13);
        uint16_t* Psq = Ps[w][qs];
        int half = (quad & 1) * 4;
        *(uint2*)(Psq + lrow * 32 + (((quad >> 1)) ^ sw) * 8 + half) = make_uint2(d0, d1);
        *(uint2*)(Psq + lrow * 32 + ((2 + (quad >> 1)) ^ sw) * 8 + half) = make_uint2(d2, d3);
      }
    }

    // ---- PV-phase: V^T A-fragments, P B-fragments, accumulate O ----
    {
      short8 vA[4];
#pragma unroll
      for (int dt = 0; dt < 4; ++dt) {
        int row = dt * 16 + lrow;
        vA[dt] = *(const short8*)(Vs + row * 32 + (quad ^ ((row >> 1) & 3)) * 8);
      }
#pragma unroll
      for (int qs = 0; qs < 4; ++qs) {
        short8 pB = *(const short8*)(Ps[w][qs] + lrow * 32 + (quad ^ sw) * 8);
#pragma unroll
        for (int dt = 0; dt < 4; ++dt)
          O[dt][qs] = __builtin_amdgcn_mfma_f32_16x16x32_bf16(vA[dt], pB, O[dt][qs], 0, 0, 0);
      }
    }
  }

  // epilogue: reduce l across quads (kv partials), normalize, write fp32
#pragma unroll
  for (int qs = 0; qs < 4; ++qs) {
    float l = l_acc[qs];
    l += __shfl_xor(l, 16);
    l += __shfl_xor(l, 32);
    float inv = 1.0f / l;
    int qg = q0 + qs * 16 + lrow;   // nb index of this lane's q column
    float* op = out + ((size_t)b * Tsz + (size_t)qg * 16 + s) * Dsz + h * 64;
#pragma unroll
    for (int dt = 0; dt < 4; ++dt) {
      float4 vv;
      vv.x = O[dt][qs][0] * inv; vv.y = O[dt][qs][1] * inv;
      vv.z = O[dt][qs][2] * inv; vv.w = O[dt][qs][3] * inv;
      *(float4*)(op + dt * 16 + quad * 4) = vv;
    }
  }
}

// ---------------- launch ----------------
extern "C" void kernel_launch(void* const* d_in, const int* in_sizes, int n_in,
                              void* d_out, int out_size, void* d_ws, size_t ws_size,
                              hipStream_t stream) {
  const float* x  = (const float*)d_in[0];
  const float* Wq = (const float*)d_in[1];
  const float* bq = (const float*)d_in[2];
  const float* Wk = (const float*)d_in[3];
  const float* bk = (const float*)d_in[4];
  const float* Wv = (const float*)d_in[5];
  const float* bv = (const float*)d_in[6];
  float* out = (float*)d_out;

  // workspace: Qp | Kp | Vtmp | xb | wc ; Vt aliases xb (gemm done with xb first)
  uint16_t* Qp   = (uint16_t*)d_ws;
  uint16_t* Kp   = Qp + (size_t)16777216;
  uint16_t* Vtmp = Kp + (size_t)16777216;
  uint16_t* xb   = Vtmp + (size_t)16777216;
  uint16_t* wc   = xb + (size_t)16777216;
  uint16_t* Vt   = xb;  // alias

  hipLaunchKernelGGL(cvt_kernel, dim3(XBLK + NQKV * Dsz / 1024), dim3(256), 0, stream,
                     x, Wq, Wk, Wv, xb, wc);
  hipLaunchKernelGGL(gemm_qkv, dim3((MROWS / BM) * (NQKV / BN)), dim3(256), 0, stream,
                     xb, wc, bq, bk, bv, Qp, Kp, Vtmp);
  hipLaunchKernelGGL(vtrans, dim3(Bsz * BSn * Hn * 8), dim3(256), 0, stream, Vtmp, Vt);
  hipLaunchKernelGGL(attn_kernel, dim3(Bsz * BSn * Hn * 2), dim3(256), 0, stream,
                     Qp, Kp, Vt, out);
}